// Round 4
// baseline (837.576 us; speedup 1.0000x reference)
//
#include <hip/hip_runtime.h>
#include <hip/hip_bf16.h>
#include <stdint.h>

#define B_   4
#define S_   2048
#define D_   1024
#define F_   4096
#define E_   8
#define KSEL 512

typedef __attribute__((ext_vector_type(8))) short short8;
typedef __attribute__((ext_vector_type(4))) float floatx4;

__device__ __forceinline__ unsigned short f2bf(float f) {
    unsigned u = __float_as_uint(f);
    unsigned r = (u + 0x7FFFu + ((u >> 16) & 1u)) >> 16;   // RNE
    return (unsigned short)r;
}

// ---------------------------------------------------------------- converts
__global__ void convert_kernel(const float* __restrict__ src,
                               unsigned short* __restrict__ dst, int n4) {
    int i = blockIdx.x * blockDim.x + threadIdx.x;
    int stride = gridDim.x * blockDim.x;
    const float4* s4 = (const float4*)src;
    ushort4* d4 = (ushort4*)dst;
    for (; i < n4; i += stride) {
        float4 v = s4[i];
        ushort4 o;
        o.x = f2bf(v.x); o.y = f2bf(v.y); o.z = f2bf(v.z); o.w = f2bf(v.w);
        d4[i] = o;
    }
}

// ---------------------------------------------------------------- router (+ x->bf16 fused)
__global__ void router_kernel(const float* __restrict__ x,
                              const float* __restrict__ choice,
                              float* __restrict__ probs,
                              unsigned short* __restrict__ xb) {
    int bs = blockIdx.x;               // 0..8191
    int b = bs >> 11, s = bs & 2047;
    int tid = threadIdx.x;
    const float4* xr = (const float4*)(x + (size_t)bs * D_);
    float4 xv = xr[tid];
    ushort4 o;
    o.x = f2bf(xv.x); o.y = f2bf(xv.y); o.z = f2bf(xv.z); o.w = f2bf(xv.w);
    ((ushort4*)(xb + (size_t)bs * D_))[tid] = o;

    float acc[E_];
#pragma unroll
    for (int e = 0; e < E_; e++) {
        const float4* cr = (const float4*)(choice + e * D_);
        float4 cv = cr[tid];
        acc[e] = xv.x * cv.x + xv.y * cv.y + xv.z * cv.z + xv.w * cv.w;
    }
    __shared__ float red[E_][4];
    int lane = tid & 63, w = tid >> 6;
#pragma unroll
    for (int e = 0; e < E_; e++) {
        float v = acc[e];
        for (int off = 32; off; off >>= 1) v += __shfl_down(v, off, 64);
        if (lane == 0) red[e][w] = v;
    }
    __syncthreads();
    if (tid == 0) {
        float l[E_], m = -1e30f;
#pragma unroll
        for (int e = 0; e < E_; e++) {
            l[e] = red[e][0] + red[e][1] + red[e][2] + red[e][3];
            m = fmaxf(m, l[e]);
        }
        float sum = 0.f, p[E_];
#pragma unroll
        for (int e = 0; e < E_; e++) { p[e] = __expf(l[e] - m); sum += p[e]; }
        float inv = 1.0f / sum;
#pragma unroll
        for (int e = 0; e < E_; e++)
            probs[((size_t)b * E_ + e) * S_ + s] = p[e] * inv;
    }
}

// ---------------------------------------------------------------- top-k by rank
__global__ void topk_kernel(const float* __restrict__ probs,
                            int* __restrict__ idxb, float* __restrict__ gateb) {
    __shared__ float ps[S_];
    int be = blockIdx.x >> 3;
    int chunk = blockIdx.x & 7;
    const float* p = probs + (size_t)be * S_;
    for (int i = threadIdx.x; i < S_; i += 256) ps[i] = p[i];
    __syncthreads();
    int t = chunk * 256 + threadIdx.x;
    float pt = ps[t];
    int rank = 0;
    for (int s = 0; s < S_; s++) {
        float v = ps[s];
        rank += (v > pt) || (v == pt && s < t);
    }
    if (rank < KSEL) {
        idxb[be * KSEL + rank] = t;
        gateb[be * KSEL + rank] = pt;
    }
}

// LDS geometry: row = 32 bf16 = 64B, padded to 80B (2-way bank aliasing = free).
// One stage = A[128 rows]*80 + B[128 rows]*80 = 10240 + 10240; 2 stages = 40960B.
#define ROWB 80
#define AHALF 10240
#define STAGEB 20480

// ---------------------------------------------------------------- GEMM1 + SiLU
// C[512,4096] = gather(xb)[512,1024] @ w1[e][4096,1024]^T ; h = silu(C) bf16
// reg-staged pipeline: load(k+1)->VGPR after barrier, ds_write before barrier.
__global__ __launch_bounds__(256) void gemm1_silu(
    const unsigned short* __restrict__ xb, const unsigned short* __restrict__ w1b,
    const int* __restrict__ idxb, unsigned short* __restrict__ hbuf) {
    __shared__ alignas(16) char Ls[2 * STAGEB];
    const int tid = threadIdx.x;
    const int blk = blockIdx.x;            // 0..4095
    const int e = blk & 7;                 // XCD id
    const int ib = blk >> 3;               // 0..511
    const int b = ib >> 7;
    const int rr = ib & 127;
    const int tile_n = rr >> 2;            // adjacent 4 blocks share B tile
    const int tile_m = rr & 3;
    const int g = b * 8 + e;

    // staging slots: s = p*256+tid (p=0,1); row = s>>2 (p adds +64), chunk = s&3
    const int r0 = tid >> 2, c0 = tid & 3;
    const int tok0 = idxb[g * KSEL + tile_m * 128 + r0];
    const int tok1 = idxb[g * KSEL + tile_m * 128 + r0 + 64];
    const char* pA0 = (const char*)xb + ((size_t)b * S_ + tok0) * 2048 + c0 * 16;
    const char* pA1 = (const char*)xb + ((size_t)b * S_ + tok1) * 2048 + c0 * 16;
    const char* pB0 = (const char*)w1b + ((size_t)e * F_ + tile_n * 128 + r0) * 2048 + c0 * 16;
    const int wof = r0 * ROWB + c0 * 16;   // slot p=1 adds 64*ROWB

    const int lane = tid & 63;
    const int wm = (tid >> 6) >> 1, wn = (tid >> 6) & 1;
    const int mrow = lane & 15;
    const int q0 = lane >> 4;

    floatx4 acc[4][4];
#pragma unroll
    for (int i = 0; i < 4; i++)
#pragma unroll
        for (int j = 0; j < 4; j++) acc[i][j] = (floatx4){0.f, 0.f, 0.f, 0.f};

    // prologue: issue loads for kt=0
    float4 sA0 = *(const float4*)(pA0);
    float4 sA1 = *(const float4*)(pA1);
    float4 sB0 = *(const float4*)(pB0);
    float4 sB1 = *(const float4*)(pB0 + 64 * 2048);

    const int ITER = D_ / 32;              // 32
    for (int kt = 0; kt < ITER; kt++) {
        char* base = Ls + (kt & 1) * STAGEB;
        // stage -> LDS (compiler waits vmcnt for the regs; loads have been in
        // flight for the whole previous compute phase)
        *(float4*)(base + wof) = sA0;
        *(float4*)(base + 64 * ROWB + wof) = sA1;
        *(float4*)(base + AHALF + wof) = sB0;
        *(float4*)(base + AHALF + 64 * ROWB + wof) = sB1;
        __syncthreads();
        // issue next loads (consumed after next barrier -> latency hidden)
        size_t off = (kt + 1 < ITER) ? (size_t)(kt + 1) * 64 : 0;
        sA0 = *(const float4*)(pA0 + off);
        sA1 = *(const float4*)(pA1 + off);
        sB0 = *(const float4*)(pB0 + off);
        sB1 = *(const float4*)(pB0 + 64 * 2048 + off);
        // compute from buf[cur]
        short8 bfr[4];
#pragma unroll
        for (int j = 0; j < 4; j++) {
            int row = wn * 64 + j * 16 + mrow;
            bfr[j] = *(const short8*)(base + AHALF + row * ROWB + q0 * 16);
        }
#pragma unroll
        for (int i = 0; i < 4; i++) {
            int row = wm * 64 + i * 16 + mrow;
            short8 af = *(const short8*)(base + row * ROWB + q0 * 16);
#pragma unroll
            for (int j = 0; j < 4; j++)
                acc[i][j] = __builtin_amdgcn_mfma_f32_16x16x32_bf16(af, bfr[j], acc[i][j], 0, 0, 0);
        }
    }

    unsigned short* hr = hbuf + (size_t)g * (KSEL * F_);
#pragma unroll
    for (int i = 0; i < 4; i++) {
#pragma unroll
        for (int r2 = 0; r2 < 4; r2++) {
            int rowc = tile_m * 128 + wm * 64 + i * 16 + (lane >> 4) * 4 + r2;
#pragma unroll
            for (int j = 0; j < 4; j++) {
                int colc = tile_n * 128 + wn * 64 + j * 16 + mrow;
                float v = acc[i][j][r2];
                float s = v / (1.0f + __expf(-v));
                hr[(size_t)rowc * F_ + colc] = f2bf(s);
            }
        }
    }
}

// ---------------------------------------------------------------- GEMM2 + gate*scatter
// C[512,1024] = h[512,4096] @ w2[e][1024,4096]^T ; out[b, idx, :] += gate*C
// split-K=2; same reg-staged pipeline.
__global__ __launch_bounds__(256) void gemm2_scatter(
    const unsigned short* __restrict__ hbuf, const unsigned short* __restrict__ w2b,
    const int* __restrict__ idxb, const float* __restrict__ gateb,
    float* __restrict__ out) {
    __shared__ alignas(16) char Ls[2 * STAGEB];
    const int tid = threadIdx.x;
    const int blk = blockIdx.x;            // 0..2047
    const int e = blk & 7;                 // XCD id
    const int ib = blk >> 3;               // 0..255
    const int b = ib >> 6;
    const int t = ib & 63;
    const int tile_m = t >> 4;             // 0..3
    const int kspl = (t >> 3) & 1;
    const int tile_n = t & 7;              // innermost: 8 consecutive blocks share A
    const int g = b * 8 + e;

    const int r0 = tid >> 2, c0 = tid & 3;
    const char* pA0 = (const char*)hbuf + ((size_t)g * KSEL + tile_m * 128 + r0) * 8192
                      + c0 * 16 + (size_t)kspl * 4096;   // kspl half: 2048 cols * 2B
    const char* pB0 = (const char*)w2b + ((size_t)e * D_ + tile_n * 128 + r0) * 8192
                      + c0 * 16 + (size_t)kspl * 4096;
    const int wof = r0 * ROWB + c0 * 16;

    const int lane = tid & 63;
    const int wm = (tid >> 6) >> 1, wn = (tid >> 6) & 1;
    const int mrow = lane & 15;
    const int q0 = lane >> 4;

    floatx4 acc[4][4];
#pragma unroll
    for (int i = 0; i < 4; i++)
#pragma unroll
        for (int j = 0; j < 4; j++) acc[i][j] = (floatx4){0.f, 0.f, 0.f, 0.f};

    float4 sA0 = *(const float4*)(pA0);
    float4 sA1 = *(const float4*)(pA0 + 64 * 8192);
    float4 sB0 = *(const float4*)(pB0);
    float4 sB1 = *(const float4*)(pB0 + 64 * 8192);

    const int ITER = (F_ / 2) / 32;        // 64
    for (int kt = 0; kt < ITER; kt++) {
        char* base = Ls + (kt & 1) * STAGEB;
        *(float4*)(base + wof) = sA0;
        *(float4*)(base + 64 * ROWB + wof) = sA1;
        *(float4*)(base + AHALF + wof) = sB0;
        *(float4*)(base + AHALF + 64 * ROWB + wof) = sB1;
        __syncthreads();
        size_t off = (kt + 1 < ITER) ? (size_t)(kt + 1) * 64 : 0;
        sA0 = *(const float4*)(pA0 + off);
        sA1 = *(const float4*)(pA0 + 64 * 8192 + off);
        sB0 = *(const float4*)(pB0 + off);
        sB1 = *(const float4*)(pB0 + 64 * 8192 + off);
        short8 bfr[4];
#pragma unroll
        for (int j = 0; j < 4; j++) {
            int row = wn * 64 + j * 16 + mrow;
            bfr[j] = *(const short8*)(base + AHALF + row * ROWB + q0 * 16);
        }
#pragma unroll
        for (int i = 0; i < 4; i++) {
            int row = wm * 64 + i * 16 + mrow;
            short8 af = *(const short8*)(base + row * ROWB + q0 * 16);
#pragma unroll
            for (int j = 0; j < 4; j++)
                acc[i][j] = __builtin_amdgcn_mfma_f32_16x16x32_bf16(af, bfr[j], acc[i][j], 0, 0, 0);
        }
    }

#pragma unroll
    for (int i = 0; i < 4; i++) {
#pragma unroll
        for (int r2 = 0; r2 < 4; r2++) {
            int rslot = tile_m * 128 + wm * 64 + i * 16 + (lane >> 4) * 4 + r2;
            int tok = idxb[g * KSEL + rslot];
            float gt = gateb[g * KSEL + rslot];
            float* orow = out + ((size_t)b * S_ + tok) * D_;
#pragma unroll
            for (int j = 0; j < 4; j++) {
                int colc = tile_n * 128 + wn * 64 + j * 16 + mrow;
                atomicAdd(&orow[colc], gt * acc[i][j][r2]);
            }
        }
    }
}

// ---------------------------------------------------------------- launch
extern "C" void kernel_launch(void* const* d_in, const int* in_sizes, int n_in,
                              void* d_out, int out_size, void* d_ws, size_t ws_size,
                              hipStream_t stream) {
    const float* x      = (const float*)d_in[0];
    const float* choice = (const float*)d_in[1];
    const float* w1     = (const float*)d_in[2];
    const float* w2     = (const float*)d_in[3];
    float* out = (float*)d_out;
    char* ws = (char*)d_ws;

    unsigned short* w1b = (unsigned short*)(ws);                  // 67,108,864
    unsigned short* w2b = (unsigned short*)(ws + 67108864);       // 67,108,864
    unsigned short* xb  = (unsigned short*)(ws + 134217728);      // 16,777,216
    unsigned short* hb  = (unsigned short*)(ws + 150994944);      // 134,217,728
    float* probs        = (float*)(ws + 285212672);               // 262,144
    int*   idxb         = (int*)(ws + 285474816);                 // 65,536
    float* gateb        = (float*)(ws + 285540352);               // 65,536

    hipMemsetAsync(d_out, 0, (size_t)out_size * sizeof(float), stream);
    convert_kernel<<<8192, 256, 0, stream>>>(w1, w1b, 8388608);
    convert_kernel<<<8192, 256, 0, stream>>>(w2, w2b, 8388608);
    router_kernel<<<B_ * S_, 256, 0, stream>>>(x, choice, probs, xb);
    topk_kernel<<<B_ * E_ * 8, 256, 0, stream>>>(probs, idxb, gateb);
    gemm1_silu<<<4096, 256, 0, stream>>>(xb, w1b, idxb, hb);
    gemm2_scatter<<<2048, 256, 0, stream>>>(hb, w2b, idxb, gateb, out);
}